// Round 1
// baseline (2415.910 us; speedup 1.0000x reference)
//
#include <hip/hip_runtime.h>
#include <math.h>

// Problem constants
#define Bc 4
#define Tc 1024
#define DMc 1024
#define Hc 16
#define DKc 64
#define BHc 64          // B*H
#define Mc 4096         // B*T
#define TD (Tc*DKc)     // 65536 elements per (b,h) slab

// ---------------------------------------------------------------------------
// GEMM: Y = X(4096 x 1024) @ W(1024 x 1024)
// MODE 0: five weight matrices (blockIdx.y selects), epilogue scatters to
//         head layout (B,H,T,DK).  MODE 1: single W, plain row-major out.
// 128x128 tile, BK=16, 256 threads, 8x8 micro-tile.
// ---------------------------------------------------------------------------
template<int MODE>
__global__ __launch_bounds__(256)
void gemm_k(const float* __restrict__ X,
            const float* __restrict__ W0, const float* __restrict__ W1,
            const float* __restrict__ W2, const float* __restrict__ W3,
            const float* __restrict__ W4,
            float* __restrict__ O0, float* __restrict__ O1,
            float* __restrict__ O2, float* __restrict__ O3,
            float* __restrict__ O4)
{
    __shared__ float As[16][128];   // [k][m] (transposed on load)
    __shared__ float Bs[16][128];   // [k][n]
    const int tid = threadIdx.x;
    const int m0  = blockIdx.x * 128;
    const int by  = blockIdx.y;

    const float* W;
    float* Op;
    int n0;
    if (MODE == 0) {
        const float* Ws[5] = {W0, W1, W2, W3, W4};
        float* Os[5] = {O0, O1, O2, O3, O4};
        W  = Ws[by >> 3];
        Op = Os[by >> 3];
        n0 = (by & 7) * 128;
    } else {
        W = W0; Op = O0; n0 = by * 128;
    }

    const int tm = tid >> 4;   // 0..15
    const int tn = tid & 15;   // 0..15

    float acc[8][8];
#pragma unroll
    for (int i = 0; i < 8; i++)
#pragma unroll
        for (int j = 0; j < 8; j++) acc[i][j] = 0.f;

#pragma unroll 1
    for (int kt = 0; kt < DMc; kt += 16) {
        __syncthreads();
#pragma unroll
        for (int i = 0; i < 2; i++) {
            int id = tid + i * 256;            // 0..511
            int row = id >> 2, kq = id & 3;    // A tile: 128 rows x 4 f4 of k
            float4 av = *(const float4*)&X[(size_t)(m0 + row) * DMc + kt + kq * 4];
            As[kq*4+0][row] = av.x; As[kq*4+1][row] = av.y;
            As[kq*4+2][row] = av.z; As[kq*4+3][row] = av.w;
            int kr = id >> 5, nq = id & 31;    // B tile: 16 k-rows x 32 f4 of n
            *(float4*)&Bs[kr][nq*4] =
                *(const float4*)&W[(size_t)(kt + kr) * DMc + n0 + nq * 4];
        }
        __syncthreads();
#pragma unroll
        for (int k = 0; k < 16; k++) {
            float4 a0 = *(const float4*)&As[k][tm*8];
            float4 a1 = *(const float4*)&As[k][tm*8+4];
            float4 b0 = *(const float4*)&Bs[k][tn*8];
            float4 b1 = *(const float4*)&Bs[k][tn*8+4];
            float aa[8] = {a0.x,a0.y,a0.z,a0.w,a1.x,a1.y,a1.z,a1.w};
            float bb[8] = {b0.x,b0.y,b0.z,b0.w,b1.x,b1.y,b1.z,b1.w};
#pragma unroll
            for (int i = 0; i < 8; i++)
#pragma unroll
                for (int j = 0; j < 8; j++) acc[i][j] += aa[i]*bb[j];
        }
    }

    if (MODE == 0) {
        // scatter to (B,H,T,DK): bh*TD + t*DK + d
        const int colbase = n0 + tn * 8;          // < 1024, within one head
        const int h  = colbase >> 6;
        const int d0 = colbase & 63;
#pragma unroll
        for (int i = 0; i < 8; i++) {
            int m = m0 + tm*8 + i;
            int b = m >> 10, t = m & 1023;
            float* dst = Op + ((size_t)(b*Hc + h)*Tc + t)*DKc + d0;
            *(float4*)dst     = make_float4(acc[i][0],acc[i][1],acc[i][2],acc[i][3]);
            *(float4*)(dst+4) = make_float4(acc[i][4],acc[i][5],acc[i][6],acc[i][7]);
        }
    } else {
#pragma unroll
        for (int i = 0; i < 8; i++) {
            int m = m0 + tm*8 + i;
            float* dst = Op + (size_t)m * DMc + n0 + tn*8;
            *(float4*)dst     = make_float4(acc[i][0],acc[i][1],acc[i][2],acc[i][3]);
            *(float4*)(dst+4) = make_float4(acc[i][4],acc[i][5],acc[i][6],acc[i][7]);
        }
    }
}

// ---------------------------------------------------------------------------
// One propagation step, flash-style (A never materialized):
//   Dout[r] = (1-lam)*Din[r] + lam * (sum_s exp(q_r.k_s/8) Din[s]) / (sum_s exp)
// Scores ~N(0,1) so no max-subtraction needed (identical softmax value).
// Block: 32 query rows of one (b,h); 256 thr; 16 key-chunks of 64.
// LDS 52 KB -> 3 blocks/CU.
// ---------------------------------------------------------------------------
__global__ __launch_bounds__(256)
void prop_k(const float* __restrict__ Q, const float* __restrict__ K,
            const float* __restrict__ DreI, const float* __restrict__ DimI,
            float* __restrict__ DreO, float* __restrict__ DimO,
            const float* __restrict__ llam)
{
    __shared__ float Kt[64][68];     // [d][key], padded for transpose writes
    __shared__ float Dt[64][64];     // [key][d], re then im
    __shared__ float Qrow[32][64];   // [r][d]
    __shared__ float P[32][64];      // [r][key] exp(scores)
    __shared__ float Lpart[32][16];
    __shared__ float Lrow[32];

    const int tid = threadIdx.x;
    const int R0  = blockIdx.x * 32;
    const int bh  = blockIdx.y;
    const float* Qh = Q    + (size_t)bh * TD;
    const float* Kh = K    + (size_t)bh * TD;
    const float* DrH = DreI + (size_t)bh * TD;
    const float* DiH = DimI + (size_t)bh * TD;

#pragma unroll
    for (int i = 0; i < 2; i++) {
        int id = tid + i*256;
        int r = id >> 4, dq = id & 15;
        *(float4*)&Qrow[r][dq*4] = *(const float4*)&Qh[(R0+r)*DKc + dq*4];
    }

    const int rA = tid >> 4;    // 0..15  (rows rA and rA+16)
    const int cg = tid & 15;    // 0..15  (phase A: keys cg*4.. ; phase B: d cg*4..)

    float ar0[4]={0,0,0,0}, ai0[4]={0,0,0,0};
    float ar1[4]={0,0,0,0}, ai1[4]={0,0,0,0};
    float lac0 = 0.f, lac1 = 0.f;

#pragma unroll 1
    for (int ch = 0; ch < 16; ch++) {
        const int key0 = ch * 64;
        __syncthreads();                         // prev-iter readers done
        // ---- load K^T tile and D-re tile
#pragma unroll
        for (int i = 0; i < 4; i++) {
            int id = tid + i*256;
            int ky = id >> 4, dq = id & 15;
            const size_t gk = (size_t)(key0 + ky) * DKc + dq*4;
            float4 kv = *(const float4*)&Kh[gk];
            Kt[dq*4+0][ky] = kv.x; Kt[dq*4+1][ky] = kv.y;
            Kt[dq*4+2][ky] = kv.z; Kt[dq*4+3][ky] = kv.w;
            *(float4*)&Dt[ky][dq*4] = *(const float4*)&DrH[gk];
        }
        __syncthreads();
        // ---- phase A: scores + exp, rows (rA, rA+16) x keys cg*4..+3
        float s0[4]={0,0,0,0}, s1[4]={0,0,0,0};
#pragma unroll
        for (int d4 = 0; d4 < 16; d4++) {
            float4 q0 = *(const float4*)&Qrow[rA][d4*4];
            float4 q1 = *(const float4*)&Qrow[rA+16][d4*4];
            float qa0[4] = {q0.x,q0.y,q0.z,q0.w};
            float qa1[4] = {q1.x,q1.y,q1.z,q1.w};
#pragma unroll
            for (int cc = 0; cc < 4; cc++) {
                float4 kv = *(const float4*)&Kt[d4*4+cc][cg*4];
                s0[0] += qa0[cc]*kv.x; s0[1] += qa0[cc]*kv.y;
                s0[2] += qa0[cc]*kv.z; s0[3] += qa0[cc]*kv.w;
                s1[0] += qa1[cc]*kv.x; s1[1] += qa1[cc]*kv.y;
                s1[2] += qa1[cc]*kv.z; s1[3] += qa1[cc]*kv.w;
            }
        }
        float p0[4], p1[4], ps0 = 0.f, ps1 = 0.f;
#pragma unroll
        for (int cc = 0; cc < 4; cc++) {
            p0[cc] = __expf(s0[cc]*0.125f); ps0 += p0[cc];
            p1[cc] = __expf(s1[cc]*0.125f); ps1 += p1[cc];
        }
        *(float4*)&P[rA][cg*4]    = make_float4(p0[0],p0[1],p0[2],p0[3]);
        *(float4*)&P[rA+16][cg*4] = make_float4(p1[0],p1[1],p1[2],p1[3]);
        Lpart[rA][cg]    = ps0;
        Lpart[rA+16][cg] = ps1;
        __syncthreads();
        // ---- phase B (re): accumulate P @ Dre ; also fold the denominators
        if (cg == 0) {
#pragma unroll
            for (int qq = 0; qq < 16; qq++) {
                lac0 += Lpart[rA][qq]; lac1 += Lpart[rA+16][qq];
            }
        }
#pragma unroll
        for (int j4 = 0; j4 < 16; j4++) {
            float4 pv0 = *(const float4*)&P[rA][j4*4];
            float4 pv1 = *(const float4*)&P[rA+16][j4*4];
            float pa0[4] = {pv0.x,pv0.y,pv0.z,pv0.w};
            float pa1[4] = {pv1.x,pv1.y,pv1.z,pv1.w};
#pragma unroll
            for (int cc = 0; cc < 4; cc++) {
                float4 dr = *(const float4*)&Dt[j4*4+cc][cg*4];
                ar0[0] += pa0[cc]*dr.x; ar0[1] += pa0[cc]*dr.y;
                ar0[2] += pa0[cc]*dr.z; ar0[3] += pa0[cc]*dr.w;
                ar1[0] += pa1[cc]*dr.x; ar1[1] += pa1[cc]*dr.y;
                ar1[2] += pa1[cc]*dr.z; ar1[3] += pa1[cc]*dr.w;
            }
        }
        __syncthreads();                         // done with Dre tile
        // ---- load D-im tile into same buffer
#pragma unroll
        for (int i = 0; i < 4; i++) {
            int id = tid + i*256;
            int ky = id >> 4, dq = id & 15;
            const size_t gk = (size_t)(key0 + ky) * DKc + dq*4;
            *(float4*)&Dt[ky][dq*4] = *(const float4*)&DiH[gk];
        }
        __syncthreads();
        // ---- phase B (im)
#pragma unroll
        for (int j4 = 0; j4 < 16; j4++) {
            float4 pv0 = *(const float4*)&P[rA][j4*4];
            float4 pv1 = *(const float4*)&P[rA+16][j4*4];
            float pa0[4] = {pv0.x,pv0.y,pv0.z,pv0.w};
            float pa1[4] = {pv1.x,pv1.y,pv1.z,pv1.w};
#pragma unroll
            for (int cc = 0; cc < 4; cc++) {
                float4 dv = *(const float4*)&Dt[j4*4+cc][cg*4];
                ai0[0] += pa0[cc]*dv.x; ai0[1] += pa0[cc]*dv.y;
                ai0[2] += pa0[cc]*dv.z; ai0[3] += pa0[cc]*dv.w;
                ai1[0] += pa1[cc]*dv.x; ai1[1] += pa1[cc]*dv.y;
                ai1[2] += pa1[cc]*dv.z; ai1[3] += pa1[cc]*dv.w;
            }
        }
    }
    __syncthreads();
    if (cg == 0) { Lrow[rA] = lac0; Lrow[rA+16] = lac1; }
    __syncthreads();

    const float il0 = 1.f / Lrow[rA];
    const float il1 = 1.f / Lrow[rA+16];
    const float lam = 1.f / (1.f + __expf(-llam[0]));
    const float oml = 1.f - lam;
    {
        const size_t g0 = (size_t)(R0 + rA) * DKc + cg*4;
        float4 dr = *(const float4*)&DrH[g0];
        float4 dv = *(const float4*)&DiH[g0];
        float4 o;
        o.x = oml*dr.x + lam*ar0[0]*il0; o.y = oml*dr.y + lam*ar0[1]*il0;
        o.z = oml*dr.z + lam*ar0[2]*il0; o.w = oml*dr.w + lam*ar0[3]*il0;
        *(float4*)&DreO[(size_t)bh*TD + g0] = o;
        o.x = oml*dv.x + lam*ai0[0]*il0; o.y = oml*dv.y + lam*ai0[1]*il0;
        o.z = oml*dv.z + lam*ai0[2]*il0; o.w = oml*dv.w + lam*ai0[3]*il0;
        *(float4*)&DimO[(size_t)bh*TD + g0] = o;

        const size_t g1 = (size_t)(R0 + rA + 16) * DKc + cg*4;
        dr = *(const float4*)&DrH[g1];
        dv = *(const float4*)&DiH[g1];
        o.x = oml*dr.x + lam*ar1[0]*il1; o.y = oml*dr.y + lam*ar1[1]*il1;
        o.z = oml*dr.z + lam*ar1[2]*il1; o.w = oml*dr.w + lam*ar1[3]*il1;
        *(float4*)&DreO[(size_t)bh*TD + g1] = o;
        o.x = oml*dv.x + lam*ai1[0]*il1; o.y = oml*dv.y + lam*ai1[1]*il1;
        o.z = oml*dv.z + lam*ai1[2]*il1; o.w = oml*dv.w + lam*ai1[3]*il1;
        *(float4*)&DimO[(size_t)bh*TD + g1] = o;
    }
}

// ---------------------------------------------------------------------------
// mean over T per (b,h,d)
// ---------------------------------------------------------------------------
__global__ __launch_bounds__(256)
void mean_k(const float* __restrict__ Dre, const float* __restrict__ Dim,
            float* __restrict__ Mre, float* __restrict__ Mim)
{
    __shared__ float sre[4][64], sim[4][64];
    const int bh = blockIdx.x;
    const int d = threadIdx.x & 63, q = threadIdx.x >> 6;
    const float* pr = Dre + (size_t)bh * TD;
    const float* pi = Dim + (size_t)bh * TD;
    float ar = 0.f, ai = 0.f;
    for (int t = q*256; t < q*256 + 256; t++) {
        ar += pr[t*64 + d]; ai += pi[t*64 + d];
    }
    sre[q][d] = ar; sim[q][d] = ai;
    __syncthreads();
    if (threadIdx.x < 64) {
        float r  = sre[0][d]+sre[1][d]+sre[2][d]+sre[3][d];
        float im = sim[0][d]+sim[1][d]+sim[2][d]+sim[3][d];
        Mre[bh*64 + d] = r  * (1.f/1024.f);
        Mim[bh*64 + d] = im * (1.f/1024.f);
    }
}

// ---------------------------------------------------------------------------
// gate = softmax_T( Re(D conj(M)) / (|D||M|+1e-8) ); also gateV in (B,T,DM)
// cos in [-1,1] -> exp without max-subtraction is exact-safe.
// ---------------------------------------------------------------------------
__global__ __launch_bounds__(256)
void gate_k(const float* __restrict__ Dre, const float* __restrict__ Dim,
            const float* __restrict__ Mre, const float* __restrict__ Mim,
            const float* __restrict__ V,
            float* __restrict__ gate_out, float* __restrict__ gateV)
{
    __shared__ float part[4][64];
    __shared__ float dinv[64];
    const int bh = blockIdx.x;
    const int d = threadIdx.x & 63, q = threadIdx.x >> 6;
    const float* pr = Dre + (size_t)bh * TD;
    const float* pi = Dim + (size_t)bh * TD;
    const float mre = Mre[bh*64 + d], mim = Mim[bh*64 + d];
    const float mabs = sqrtf(mre*mre + mim*mim);

    float ps = 0.f;
    for (int t = q*256; t < (q+1)*256; t++) {
        float dr = pr[t*64 + d], dv = pi[t*64 + d];
        float c = (dr*mre + dv*mim) / (sqrtf(dr*dr + dv*dv)*mabs + 1e-8f);
        ps += __expf(c);
    }
    part[q][d] = ps;
    __syncthreads();
    if (threadIdx.x < 64)
        dinv[d] = 1.f / (part[0][d]+part[1][d]+part[2][d]+part[3][d]);
    __syncthreads();

    const float di_ = dinv[d];
    const int b = bh >> 4, h = bh & 15;
    const float* pv = V + (size_t)bh * TD;
    for (int t = q*256; t < (q+1)*256; t++) {
        float dr = pr[t*64 + d], dv = pi[t*64 + d];
        float c = (dr*mre + dv*mim) / (sqrtf(dr*dr + dv*dv)*mabs + 1e-8f);
        float g = __expf(c) * di_;
        gate_out[(size_t)bh*TD + t*64 + d] = g;
        gateV[((size_t)b*Tc + t)*DMc + h*64 + d] = g * pv[t*64 + d];
    }
}

// ---------------------------------------------------------------------------
extern "C" void kernel_launch(void* const* d_in, const int* in_sizes, int n_in,
                              void* d_out, int out_size, void* d_ws, size_t ws_size,
                              hipStream_t stream)
{
    const float* x    = (const float*)d_in[0];
    const float* W_Q  = (const float*)d_in[1];
    const float* W_K  = (const float*)d_in[2];
    const float* W_re = (const float*)d_in[3];
    const float* W_im = (const float*)d_in[4];
    const float* W_V  = (const float*)d_in[5];
    const float* W_O  = (const float*)d_in[6];
    const float* llam = (const float*)d_in[7];

    float* out      = (float*)d_out;
    float* gate_out = out + (size_t)Mc * DMc;   // second output, (B,H,T,DK)

    float* ws = (float*)d_ws;
    const size_t S = (size_t)BHc * TD;          // 4M floats per slab
    float* Q    = ws;
    float* K    = ws + S;
    float* V    = ws + 2*S;
    float* D0re = ws + 3*S;
    float* D0im = ws + 4*S;
    float* D1re = ws + 5*S;
    float* D1im = ws + 6*S;
    float* Mre  = ws + 7*S;
    float* Mim  = Mre + BHc*DKc;
    float* gateV = Q;                           // Q dead after propagation

    // projections: Q,K,Dre,Dim,V  (head layout)
    gemm_k<0><<<dim3(32, 40), 256, 0, stream>>>(
        x, W_Q, W_K, W_re, W_im, W_V, Q, K, D0re, D0im, V);

    // 3 propagation steps (same A each time, recomputed from Q,K)
    prop_k<<<dim3(32, 64), 256, 0, stream>>>(Q, K, D0re, D0im, D1re, D1im, llam);
    prop_k<<<dim3(32, 64), 256, 0, stream>>>(Q, K, D1re, D1im, D0re, D0im, llam);
    prop_k<<<dim3(32, 64), 256, 0, stream>>>(Q, K, D0re, D0im, D1re, D1im, llam);

    mean_k<<<64, 256, 0, stream>>>(D1re, D1im, Mre, Mim);
    gate_k<<<64, 256, 0, stream>>>(D1re, D1im, Mre, Mim, V, gate_out, gateV);

    // out = gateV @ W_O
    gemm_k<1><<<dim3(32, 8), 256, 0, stream>>>(
        gateV, W_O, W_O, W_O, W_O, W_O, out, out, out, out, out);
}

// Round 3
// 1253.292 us; speedup vs baseline: 1.9277x; 1.9277x over previous
//
#include <hip/hip_runtime.h>
#include <math.h>

// Problem constants
#define Bc 4
#define Tc 1024
#define DMc 1024
#define Hc 16
#define DKc 64
#define BHc 64          // B*H
#define Mc 4096         // B*T
#define TD (Tc*DKc)     // 65536 el per (b,h) slab, stride-64 layout
#define TD2 (Tc*128)    // combined re|im slab, stride-128 layout

typedef __bf16 bf16_t;
typedef bf16_t bf16x4 __attribute__((ext_vector_type(4)));
typedef bf16_t bf16x8 __attribute__((ext_vector_type(8)));
typedef float  f32x4  __attribute__((ext_vector_type(4)));

#define KSTR 68   // LDS stride for 64-wide rows (bf16): 136B, 8B-aligned
#define SSTR 36   // LDS stride for 32-wide rows (bf16): 72B, 8B-aligned

__device__ __forceinline__ bf16x8 ld8(const bf16_t* p) {
    union { bf16x8 v; struct { bf16x4 a, b; } s; } u;
    u.s.a = *(const bf16x4*)p;
    u.s.b = *(const bf16x4*)(p + 4);
    return u.v;
}
// split f32x4 -> bf16 hi + bf16 lo (lo = exact f32 residual rounded to bf16)
__device__ __forceinline__ void packsplit4(bf16_t* dh, bf16_t* dl, float4 v) {
    bf16x4 h, l;
    h[0]=(bf16_t)v.x; l[0]=(bf16_t)(v.x-(float)h[0]);
    h[1]=(bf16_t)v.y; l[1]=(bf16_t)(v.y-(float)h[1]);
    h[2]=(bf16_t)v.z; l[2]=(bf16_t)(v.z-(float)h[2]);
    h[3]=(bf16_t)v.w; l[3]=(bf16_t)(v.w-(float)h[3]);
    *(bf16x4*)dh = h; *(bf16x4*)dl = l;
}

// ---------------------------------------------------------------------------
// GEMM: Y = X(4096 x 1024) @ W(1024 x 1024)  (f32, vector ALU)
// MODE 0: 5 weights; outputs 0,1,4 -> head slabs [bh][t][64];
//         outputs 2,3 -> combined D [bh][t][128] (re cols 0-63 / im 64-127).
// MODE 1: single W, row-major out.
// ---------------------------------------------------------------------------
template<int MODE>
__global__ __launch_bounds__(256)
void gemm_k(const float* __restrict__ X,
            const float* __restrict__ W0, const float* __restrict__ W1,
            const float* __restrict__ W2, const float* __restrict__ W3,
            const float* __restrict__ W4,
            float* __restrict__ O0, float* __restrict__ O1,
            float* __restrict__ O2, float* __restrict__ O3,
            float* __restrict__ O4)
{
    __shared__ float As[16][128];
    __shared__ float Bs[16][128];
    const int tid = threadIdx.x;
    const int m0  = blockIdx.x * 128;
    const int by  = blockIdx.y;

    const float* W;
    float* Op;
    int n0, ostr;
    if (MODE == 0) {
        const float* Ws[5] = {W0, W1, W2, W3, W4};
        float* Os[5] = {O0, O1, O2, O3, O4};
        const int sel = by >> 3;
        W  = Ws[sel];
        Op = Os[sel];
        n0 = (by & 7) * 128;
        ostr = (sel == 2 || sel == 3) ? 128 : 64;
    } else {
        W = W0; Op = O0; n0 = by * 128; ostr = 0;
    }

    const int tm = tid >> 4;
    const int tn = tid & 15;

    float acc[8][8];
#pragma unroll
    for (int i = 0; i < 8; i++)
#pragma unroll
        for (int j = 0; j < 8; j++) acc[i][j] = 0.f;

#pragma unroll 1
    for (int kt = 0; kt < DMc; kt += 16) {
        __syncthreads();
#pragma unroll
        for (int i = 0; i < 2; i++) {
            int id = tid + i * 256;
            int row = id >> 2, kq = id & 3;
            float4 av = *(const float4*)&X[(size_t)(m0 + row) * DMc + kt + kq * 4];
            As[kq*4+0][row] = av.x; As[kq*4+1][row] = av.y;
            As[kq*4+2][row] = av.z; As[kq*4+3][row] = av.w;
            int kr = id >> 5, nq = id & 31;
            *(float4*)&Bs[kr][nq*4] =
                *(const float4*)&W[(size_t)(kt + kr) * DMc + n0 + nq * 4];
        }
        __syncthreads();
#pragma unroll
        for (int k = 0; k < 16; k++) {
            float4 a0 = *(const float4*)&As[k][tm*8];
            float4 a1 = *(const float4*)&As[k][tm*8+4];
            float4 b0 = *(const float4*)&Bs[k][tn*8];
            float4 b1 = *(const float4*)&Bs[k][tn*8+4];
            float aa[8] = {a0.x,a0.y,a0.z,a0.w,a1.x,a1.y,a1.z,a1.w};
            float bb[8] = {b0.x,b0.y,b0.z,b0.w,b1.x,b1.y,b1.z,b1.w};
#pragma unroll
            for (int i = 0; i < 8; i++)
#pragma unroll
                for (int j = 0; j < 8; j++) acc[i][j] += aa[i]*bb[j];
        }
    }

    if (MODE == 0) {
        const int colbase = n0 + tn * 8;
        const int h  = colbase >> 6;
        const int d0 = colbase & 63;
#pragma unroll
        for (int i = 0; i < 8; i++) {
            int m = m0 + tm*8 + i;
            int b = m >> 10, t = m & 1023;
            float* dst = Op + ((size_t)(b*Hc + h)*Tc + t)*ostr + d0;
            *(float4*)dst     = make_float4(acc[i][0],acc[i][1],acc[i][2],acc[i][3]);
            *(float4*)(dst+4) = make_float4(acc[i][4],acc[i][5],acc[i][6],acc[i][7]);
        }
    } else {
#pragma unroll
        for (int i = 0; i < 8; i++) {
            int m = m0 + tm*8 + i;
            float* dst = Op + (size_t)m * DMc + n0 + tn*8;
            *(float4*)dst     = make_float4(acc[i][0],acc[i][1],acc[i][2],acc[i][3]);
            *(float4*)(dst+4) = make_float4(acc[i][4],acc[i][5],acc[i][6],acc[i][7]);
        }
    }
}

// ---------------------------------------------------------------------------
// Transpose D: [bh][t][128] f32 -> [bh][128][t] f32
// ---------------------------------------------------------------------------
__global__ __launch_bounds__(256)
void transpose_k(const float* __restrict__ Din, float* __restrict__ DoutT)
{
    __shared__ float tile[32][33];
    const int bh = blockIdx.z;
    const int t0 = blockIdx.x * 32, d0 = blockIdx.y * 32;
    const int tx = threadIdx.x & 31, ty = threadIdx.x >> 5;
    const float* src = Din   + (size_t)bh * TD2;
    float* dst       = DoutT + (size_t)bh * TD2;
#pragma unroll
    for (int i = 0; i < 4; i++)
        tile[ty + 8*i][tx] = src[(size_t)(t0 + ty + 8*i)*128 + d0 + tx];
    __syncthreads();
#pragma unroll
    for (int i = 0; i < 4; i++)
        dst[(size_t)(d0 + ty + 8*i)*Tc + t0 + tx] = tile[tx][ty + 8*i];
}

// ---------------------------------------------------------------------------
// Fused propagation step, SPLIT-bf16 MFMA (hi+lo pairs -> ~f32 precision).
//   DoutT[d][t] = (1-lam)*DinT[d][t] + (lam/L[t]) * sum_s DinT[d][s]*exp(q_t.k_s/8)
// Block: one bh x 128 t_out rows; s-loop in 32 chunks of 32.
// Q fragments live in registers (loop-invariant). LDS = 46 KB.
// FINAL=1 writes [t][d] combined layout; else [d][t].
// ---------------------------------------------------------------------------
template<int FINAL>
__global__ __launch_bounds__(256)
void prop_k(const float* __restrict__ Qg, const float* __restrict__ Kg,
            const float* __restrict__ DinT, float* __restrict__ Dout,
            const float* __restrict__ llam)
{
    __shared__ bf16_t Ksh[32*KSTR], Ksl[32*KSTR];   // K chunk [s][dk]
    __shared__ bf16_t Dsh[128*SSTR], Dsl[128*SSTR]; // D chunk [d][s]
    __shared__ bf16_t Psh[128*SSTR], Psl[128*SSTR]; // P chunk [t][s]
    __shared__ float  Lrow[128];

    const int tid = threadIdx.x;
    const int wv  = tid >> 6;        // wave 0..3
    const int ln  = tid & 63;
    const int l15 = ln & 15;
    const int qd  = ln >> 4;         // quad 0..3
    const int bh  = blockIdx.y;
    const int T0  = blockIdx.x * 128;

    const float* Qh  = Qg   + (size_t)bh * TD;
    const float* Kh  = Kg   + (size_t)bh * TD;
    const float* DTh = DinT + (size_t)bh * TD2;

    // ---- Q fragments in registers (A-layout: m=l15, k=qd*8+j), hi+lo split
    bf16x8 qh[2][2], ql[2][2];
#pragma unroll
    for (int ti = 0; ti < 2; ti++) {
        const float* qp = &Qh[(size_t)(T0 + (2*wv + ti)*16 + l15) * DKc];
#pragma unroll
        for (int ks = 0; ks < 2; ks++) {
            float4 a = *(const float4*)&qp[ks*32 + qd*8];
            float4 b = *(const float4*)&qp[ks*32 + qd*8 + 4];
            float v8[8] = {a.x,a.y,a.z,a.w,b.x,b.y,b.z,b.w};
#pragma unroll
            for (int j = 0; j < 8; j++) {
                qh[ti][ks][j] = (bf16_t)v8[j];
                ql[ti][ks][j] = (bf16_t)(v8[j] - (float)qh[ti][ks][j]);
            }
        }
    }

    f32x4 acc[4][4];
#pragma unroll
    for (int i = 0; i < 4; i++)
#pragma unroll
        for (int j = 0; j < 4; j++) acc[i][j] = (f32x4)0.f;
    float rs[2][4] = {{0.f,0.f,0.f,0.f},{0.f,0.f,0.f,0.f}};

#pragma unroll 1
    for (int ch = 0; ch < 32; ch++) {
        const int s0 = ch * 32;
        __syncthreads();                       // prev chunk fully consumed
        // ---- stage K chunk (32 x 64) split
#pragma unroll
        for (int i = 0; i < 2; i++) {
            int id = tid + i*256;
            int r = id >> 4, c4 = (id & 15) * 4;
            float4 v = *(const float4*)&Kh[(size_t)(s0 + r)*DKc + c4];
            packsplit4(&Ksh[r*KSTR + c4], &Ksl[r*KSTR + c4], v);
        }
        // ---- stage D chunk (128 x 32) split
#pragma unroll
        for (int i = 0; i < 4; i++) {
            int id = tid + i*256;
            int r = id >> 3, c4 = (id & 7) * 4;
            float4 v = *(const float4*)&DTh[(size_t)r*Tc + s0 + c4];
            packsplit4(&Dsh[r*SSTR + c4], &Dsl[r*SSTR + c4], v);
        }
        __syncthreads();
        // ---- scores: wave -> t-tiles {2wv,2wv+1} x s-tiles {0,1}
        f32x4 pacc[2][2];
#pragma unroll
        for (int ti = 0; ti < 2; ti++)
#pragma unroll
            for (int si = 0; si < 2; si++) pacc[ti][si] = (f32x4)0.f;
#pragma unroll
        for (int ks = 0; ks < 2; ks++) {
            bf16x8 kbh[2], kbl[2];
#pragma unroll
            for (int si = 0; si < 2; si++) {
                kbh[si] = ld8(&Ksh[(si*16 + l15)*KSTR + ks*32 + qd*8]);
                kbl[si] = ld8(&Ksl[(si*16 + l15)*KSTR + ks*32 + qd*8]);
            }
#pragma unroll
            for (int ti = 0; ti < 2; ti++)
#pragma unroll
                for (int si = 0; si < 2; si++) {
                    pacc[ti][si] = __builtin_amdgcn_mfma_f32_16x16x32_bf16(
                        qh[ti][ks], kbh[si], pacc[ti][si], 0, 0, 0);
                    pacc[ti][si] = __builtin_amdgcn_mfma_f32_16x16x32_bf16(
                        ql[ti][ks], kbh[si], pacc[ti][si], 0, 0, 0);
                    pacc[ti][si] = __builtin_amdgcn_mfma_f32_16x16x32_bf16(
                        qh[ti][ks], kbl[si], pacc[ti][si], 0, 0, 0);
                }
        }
        // exp (f32), row-sum accumulate, split-store P
#pragma unroll
        for (int ti = 0; ti < 2; ti++)
#pragma unroll
            for (int si = 0; si < 2; si++)
#pragma unroll
                for (int r = 0; r < 4; r++) {
                    float e = __expf(pacc[ti][si][r] * 0.125f);
                    rs[ti][r] += e;
                    int t = (2*wv + ti)*16 + qd*4 + r;
                    int s = si*16 + l15;
                    bf16_t eh = (bf16_t)e;
                    Psh[t*SSTR + s] = eh;
                    Psl[t*SSTR + s] = (bf16_t)(e - (float)eh);
                }
        __syncthreads();
        // ---- P@D: wave quadrant d-half = wv>>1, t-half = wv&1, K=32
        bf16x8 adh[4], adl[4], pbh[4], pbl[4];
#pragma unroll
        for (int it = 0; it < 4; it++) {
            int row = ((wv>>1)*64 + it*16 + l15)*SSTR + qd*8;
            adh[it] = ld8(&Dsh[row]);
            adl[it] = ld8(&Dsl[row]);
        }
#pragma unroll
        for (int jt = 0; jt < 4; jt++) {
            int row = ((wv&1)*64 + jt*16 + l15)*SSTR + qd*8;
            pbh[jt] = ld8(&Psh[row]);
            pbl[jt] = ld8(&Psl[row]);
        }
#pragma unroll
        for (int it = 0; it < 4; it++)
#pragma unroll
            for (int jt = 0; jt < 4; jt++) {
                acc[it][jt] = __builtin_amdgcn_mfma_f32_16x16x32_bf16(
                    adh[it], pbh[jt], acc[it][jt], 0, 0, 0);
                acc[it][jt] = __builtin_amdgcn_mfma_f32_16x16x32_bf16(
                    adh[it], pbl[jt], acc[it][jt], 0, 0, 0);
                acc[it][jt] = __builtin_amdgcn_mfma_f32_16x16x32_bf16(
                    adl[it], pbh[jt], acc[it][jt], 0, 0, 0);
            }
    }

    // ---- finalize row sums (reduce across l15 = lane bits 0..3)
#pragma unroll
    for (int ti = 0; ti < 2; ti++)
#pragma unroll
        for (int r = 0; r < 4; r++) {
            float v = rs[ti][r];
            v += __shfl_xor(v, 1);  v += __shfl_xor(v, 2);
            v += __shfl_xor(v, 4);  v += __shfl_xor(v, 8);
            rs[ti][r] = v;
        }
    __syncthreads();
    if (l15 == 0) {
#pragma unroll
        for (int ti = 0; ti < 2; ti++)
#pragma unroll
            for (int r = 0; r < 4; r++)
                Lrow[(2*wv + ti)*16 + qd*4 + r] = rs[ti][r];
    }
    __syncthreads();

    const float lam = 1.f / (1.f + __expf(-llam[0]));
    const float oml = 1.f - lam;

#pragma unroll
    for (int jt = 0; jt < 4; jt++) {
        const int t = (wv&1)*64 + jt*16 + l15;         // C col
        const float s = lam / Lrow[t];
#pragma unroll
        for (int it = 0; it < 4; it++) {
            const int d0 = (wv>>1)*64 + it*16 + qd*4;  // C rows d0..d0+3
            float v[4];
#pragma unroll
            for (int r = 0; r < 4; r++) {
                float res = DTh[(size_t)(d0 + r)*Tc + T0 + t];
                v[r] = oml*res + s*acc[it][jt][r];
            }
            if (FINAL) {
                *(float4*)&Dout[((size_t)bh*Tc + T0 + t)*128 + d0] =
                    make_float4(v[0], v[1], v[2], v[3]);
            } else {
#pragma unroll
                for (int r = 0; r < 4; r++)
                    Dout[((size_t)bh*128 + d0 + r)*Tc + T0 + t] = v[r];
            }
        }
    }
}

// ---------------------------------------------------------------------------
// mean over T per (b,h,d)  — D in combined [bh][t][128] layout
// ---------------------------------------------------------------------------
__global__ __launch_bounds__(256)
void mean_k(const float* __restrict__ D,
            float* __restrict__ Mre, float* __restrict__ Mim)
{
    __shared__ float sre[4][64], sim[4][64];
    const int bh = blockIdx.x;
    const int d = threadIdx.x & 63, q = threadIdx.x >> 6;
    const float* p = D + (size_t)bh * TD2;
    float ar = 0.f, ai = 0.f;
    for (int t = q*256; t < q*256 + 256; t++) {
        ar += p[t*128 + d]; ai += p[t*128 + 64 + d];
    }
    sre[q][d] = ar; sim[q][d] = ai;
    __syncthreads();
    if (threadIdx.x < 64) {
        float r  = sre[0][d]+sre[1][d]+sre[2][d]+sre[3][d];
        float im = sim[0][d]+sim[1][d]+sim[2][d]+sim[3][d];
        Mre[bh*64 + d] = r  * (1.f/1024.f);
        Mim[bh*64 + d] = im * (1.f/1024.f);
    }
}

// ---------------------------------------------------------------------------
// gate softmax over T + value gating
// ---------------------------------------------------------------------------
__global__ __launch_bounds__(256)
void gate_k(const float* __restrict__ D,
            const float* __restrict__ Mre, const float* __restrict__ Mim,
            const float* __restrict__ V,
            float* __restrict__ gate_out, float* __restrict__ gateV)
{
    __shared__ float part[4][64];
    __shared__ float dinv[64];
    const int bh = blockIdx.x;
    const int d = threadIdx.x & 63, q = threadIdx.x >> 6;
    const float* p = D + (size_t)bh * TD2;
    const float mre = Mre[bh*64 + d], mim = Mim[bh*64 + d];
    const float mabs = sqrtf(mre*mre + mim*mim);

    float ps = 0.f;
    for (int t = q*256; t < (q+1)*256; t++) {
        float dr = p[t*128 + d], dv = p[t*128 + 64 + d];
        float c = (dr*mre + dv*mim) / (sqrtf(dr*dr + dv*dv)*mabs + 1e-8f);
        ps += __expf(c);
    }
    part[q][d] = ps;
    __syncthreads();
    if (threadIdx.x < 64)
        dinv[d] = 1.f / (part[0][d]+part[1][d]+part[2][d]+part[3][d]);
    __syncthreads();

    const float di_ = dinv[d];
    const int b = bh >> 4, h = bh & 15;
    const float* pv = V + (size_t)bh * TD;
    for (int t = q*256; t < (q+1)*256; t++) {
        float dr = p[t*128 + d], dv = p[t*128 + 64 + d];
        float c = (dr*mre + dv*mim) / (sqrtf(dr*dr + dv*dv)*mabs + 1e-8f);
        float g = __expf(c) * di_;
        gate_out[(size_t)bh*TD + t*64 + d] = g;
        gateV[((size_t)b*Tc + t)*DMc + h*64 + d] = g * pv[t*64 + d];
    }
}

// ---------------------------------------------------------------------------
extern "C" void kernel_launch(void* const* d_in, const int* in_sizes, int n_in,
                              void* d_out, int out_size, void* d_ws, size_t ws_size,
                              hipStream_t stream)
{
    const float* x    = (const float*)d_in[0];
    const float* W_Q  = (const float*)d_in[1];
    const float* W_K  = (const float*)d_in[2];
    const float* W_re = (const float*)d_in[3];
    const float* W_im = (const float*)d_in[4];
    const float* W_V  = (const float*)d_in[5];
    const float* W_O  = (const float*)d_in[6];
    const float* llam = (const float*)d_in[7];

    float* out      = (float*)d_out;
    float* gate_out = out + (size_t)Mc * DMc;

    float* ws = (float*)d_ws;
    const size_t S = (size_t)BHc * TD;   // 4M floats
    float* Q    = ws;                    // 16 MB
    float* K    = ws + S;                // 16 MB
    float* V    = ws + 2*S;              // 16 MB
    float* Dc   = ws + 3*S;              // 32 MB  combined [bh][t][128]
    float* DT0  = ws + 5*S;              // 32 MB  [bh][128][t]
    float* DT1  = ws + 7*S;              // 32 MB
    float* Mre  = ws + 9*S;
    float* Mim  = Mre + BHc*DKc;
    float* gateV = Q;                    // Q dead after propagation

    // projections: Q,K -> slabs; Dre/Dim -> combined Dc; V -> slab
    gemm_k<0><<<dim3(32, 40), 256, 0, stream>>>(
        x, W_Q, W_K, W_re, W_im, W_V, Q, K, Dc, Dc + 64, V);

    transpose_k<<<dim3(32, 4, 64), 256, 0, stream>>>(Dc, DT0);

    prop_k<0><<<dim3(8, 64), 256, 0, stream>>>(Q, K, DT0, DT1, llam);
    prop_k<0><<<dim3(8, 64), 256, 0, stream>>>(Q, K, DT1, DT0, llam);
    prop_k<1><<<dim3(8, 64), 256, 0, stream>>>(Q, K, DT0, Dc, llam);

    mean_k<<<64, 256, 0, stream>>>(Dc, Mre, Mim);
    gate_k<<<64, 256, 0, stream>>>(Dc, Mre, Mim, V, gate_out, gateV);

    gemm_k<1><<<dim3(32, 8), 256, 0, stream>>>(
        gateV, W_O, W_O, W_O, W_O, W_O, out, out, out, out, out);
}

// Round 4
// 836.253 us; speedup vs baseline: 2.8890x; 1.4987x over previous
//
#include <hip/hip_runtime.h>
#include <math.h>

// Problem constants
#define Bc 4
#define Tc 1024
#define DMc 1024
#define Hc 16
#define DKc 64
#define BHc 64          // B*H
#define Mc 4096         // B*T
#define TD (Tc*DKc)     // 65536 el per (b,h) slab, stride-64 layout
#define TD2 (Tc*128)    // combined re|im slab, stride-128 layout

typedef __bf16 bf16_t;
typedef bf16_t bf16x4 __attribute__((ext_vector_type(4)));
typedef bf16_t bf16x8 __attribute__((ext_vector_type(8)));
typedef float  f32x4  __attribute__((ext_vector_type(4)));

#define KSTR 68   // prop_k: LDS stride for 64-wide rows (bf16)
#define SSTR 36   // prop_k: LDS stride for 32-wide rows (bf16)
#define GSTR 40   // mgemm: LDS stride for 32-wide rows (80 B, 16B-aligned)

__device__ __forceinline__ bf16x8 ld8(const bf16_t* p) {
    union { bf16x8 v; struct { bf16x4 a, b; } s; } u;
    u.s.a = *(const bf16x4*)p;
    u.s.b = *(const bf16x4*)(p + 4);
    return u.v;
}
// split f32x4 -> bf16 hi + bf16 lo (lo = f32 residual rounded to bf16)
__device__ __forceinline__ void packsplit4(bf16_t* dh, bf16_t* dl, float4 v) {
    bf16x4 h, l;
    h[0]=(bf16_t)v.x; l[0]=(bf16_t)(v.x-(float)h[0]);
    h[1]=(bf16_t)v.y; l[1]=(bf16_t)(v.y-(float)h[1]);
    h[2]=(bf16_t)v.z; l[2]=(bf16_t)(v.z-(float)h[2]);
    h[3]=(bf16_t)v.w; l[3]=(bf16_t)(v.w-(float)h[3]);
    *(bf16x4*)dh = h; *(bf16x4*)dl = l;
}

// ---------------------------------------------------------------------------
// Convert x (4096x1024 f32) -> xh, xl bf16 (same layout)
// ---------------------------------------------------------------------------
__global__ __launch_bounds__(256)
void convx_k(const float* __restrict__ x,
             bf16_t* __restrict__ xh, bf16_t* __restrict__ xl)
{
    size_t i = ((size_t)blockIdx.x * 256 + threadIdx.x) * 4;
    float4 v = *(const float4*)&x[i];
    packsplit4(&xh[i], &xl[i], v);
}

// ---------------------------------------------------------------------------
// Convert + transpose each W (1024x1024 f32, [k][n]) -> WT hi/lo bf16 [n][k].
// Weight wi occupies WT + wi*2M bf16 (hi), +1M (lo).
// ---------------------------------------------------------------------------
__global__ __launch_bounds__(256)
void convw_k(const float* __restrict__ W0, const float* __restrict__ W1,
             const float* __restrict__ W2, const float* __restrict__ W3,
             const float* __restrict__ W4, const float* __restrict__ W5,
             bf16_t* __restrict__ WT)
{
    __shared__ float tile[32][33];
    const float* Ws[6] = {W0, W1, W2, W3, W4, W5};
    const int wi = blockIdx.z;
    const float* W = Ws[wi];
    bf16_t* WTh = WT + (size_t)wi * 2097152;
    bf16_t* WTl = WTh + 1048576;

    const int tx = threadIdx.x & 31, ty = threadIdx.x >> 5;   // ty 0..7
    const int k0 = blockIdx.x * 32, n0 = blockIdx.y * 32;
#pragma unroll
    for (int i = 0; i < 4; i++)
        tile[ty + 8*i][tx] = W[(size_t)(k0 + ty + 8*i) * DMc + n0 + tx];
    __syncthreads();
    const int kg = threadIdx.x & 7, n = threadIdx.x >> 3;     // n 0..31
    float4 v = make_float4(tile[kg*4+0][n], tile[kg*4+1][n],
                           tile[kg*4+2][n], tile[kg*4+3][n]);
    const size_t o = (size_t)(n0 + n) * DMc + k0 + kg*4;
    packsplit4(&WTh[o], &WTl[o], v);
}

// ---------------------------------------------------------------------------
// Split-bf16 MFMA GEMM: C(128x128/block) = A(Mx1024) @ WT^T, f32 accum,
// 3 products (AhBh + AhBl + AlBh). A is [m][k] bf16 hi/lo; B is WT [n][k].
// MODE 0: 5 weights (blockIdx.y>>3 selects), epilogue scatters to head slabs
//         (Q/K/V ostr 64; Dre/Dim -> combined Dc ostr 128).
// MODE 1: single weight, row-major f32 out.
// ---------------------------------------------------------------------------
template<int MODE>
__global__ __launch_bounds__(256)
void mgemm_k(const bf16_t* __restrict__ Ah, const bf16_t* __restrict__ Al,
             const bf16_t* __restrict__ WT,
             float* __restrict__ O0, float* __restrict__ O1,
             float* __restrict__ O2, float* __restrict__ O3,
             float* __restrict__ O4)
{
    __shared__ bf16_t Ash[128*GSTR], Asl[128*GSTR];
    __shared__ bf16_t Bsh[128*GSTR], Bsl[128*GSTR];

    const int tid = threadIdx.x;
    const int wv  = tid >> 6;
    const int ln  = tid & 63;
    const int l15 = ln & 15;
    const int qd  = ln >> 4;
    const int m0  = blockIdx.x * 128;
    const int by  = blockIdx.y;

    const bf16_t *Bh, *Bl;
    float* Op;
    int n0, ostr;
    if (MODE == 0) {
        const int sel = by >> 3;
        n0 = (by & 7) * 128;
        float* Os[5] = {O0, O1, O2, O3, O4};
        Op = Os[sel];
        Bh = WT + (size_t)sel * 2097152;
        Bl = Bh + 1048576;
        ostr = (sel == 2 || sel == 3) ? 128 : 64;
    } else {
        Bh = WT + (size_t)5 * 2097152;
        Bl = Bh + 1048576;
        Op = O0; n0 = by * 128; ostr = 0;
    }

    const int srow  = tid >> 1;          // 0..127
    const int shalf = (tid & 1) * 16;    // elem offset 0 / 16

    f32x4 acc[4][4];
#pragma unroll
    for (int i = 0; i < 4; i++)
#pragma unroll
        for (int j = 0; j < 4; j++) acc[i][j] = (f32x4)0.f;

#pragma unroll 1
    for (int kt = 0; kt < DMc; kt += 32) {
        __syncthreads();
        {
            const size_t ga = (size_t)(m0 + srow) * DMc + kt + shalf;
            bf16x8 a0 = *(const bf16x8*)&Ah[ga];
            bf16x8 a1 = *(const bf16x8*)&Ah[ga + 8];
            bf16x8 a2 = *(const bf16x8*)&Al[ga];
            bf16x8 a3 = *(const bf16x8*)&Al[ga + 8];
            const size_t gb = (size_t)(n0 + srow) * DMc + kt + shalf;
            bf16x8 b0 = *(const bf16x8*)&Bh[gb];
            bf16x8 b1 = *(const bf16x8*)&Bh[gb + 8];
            bf16x8 b2 = *(const bf16x8*)&Bl[gb];
            bf16x8 b3 = *(const bf16x8*)&Bl[gb + 8];
            const int lo = srow * GSTR + shalf;
            *(bf16x8*)&Ash[lo]     = a0;
            *(bf16x8*)&Ash[lo + 8] = a1;
            *(bf16x8*)&Asl[lo]     = a2;
            *(bf16x8*)&Asl[lo + 8] = a3;
            *(bf16x8*)&Bsh[lo]     = b0;
            *(bf16x8*)&Bsh[lo + 8] = b1;
            *(bf16x8*)&Bsl[lo]     = b2;
            *(bf16x8*)&Bsl[lo + 8] = b3;
        }
        __syncthreads();

        bf16x8 fah[4], fal[4], fbh[4], fbl[4];
#pragma unroll
        for (int it = 0; it < 4; it++) {
            const int row = ((wv>>1)*64 + it*16 + l15) * GSTR + qd*8;
            fah[it] = ld8(&Ash[row]);
            fal[it] = ld8(&Asl[row]);
        }
#pragma unroll
        for (int jt = 0; jt < 4; jt++) {
            const int row = ((wv&1)*64 + jt*16 + l15) * GSTR + qd*8;
            fbh[jt] = ld8(&Bsh[row]);
            fbl[jt] = ld8(&Bsl[row]);
        }
#pragma unroll
        for (int it = 0; it < 4; it++)
#pragma unroll
            for (int jt = 0; jt < 4; jt++) {
                acc[it][jt] = __builtin_amdgcn_mfma_f32_16x16x32_bf16(
                    fah[it], fbh[jt], acc[it][jt], 0, 0, 0);
                acc[it][jt] = __builtin_amdgcn_mfma_f32_16x16x32_bf16(
                    fah[it], fbl[jt], acc[it][jt], 0, 0, 0);
                acc[it][jt] = __builtin_amdgcn_mfma_f32_16x16x32_bf16(
                    fal[it], fbh[jt], acc[it][jt], 0, 0, 0);
            }
    }

    // epilogue: C[m][n], m = row (qd*4+r), n = col (l15)
#pragma unroll
    for (int it = 0; it < 4; it++) {
        const int mb = m0 + (wv>>1)*64 + it*16 + qd*4;
#pragma unroll
        for (int jt = 0; jt < 4; jt++) {
            const int col = n0 + (wv&1)*64 + jt*16 + l15;
            if (MODE == 0) {
                const int hh = col >> 6, d = col & 63;
#pragma unroll
                for (int r = 0; r < 4; r++) {
                    const int m = mb + r;
                    const int b = m >> 10, t = m & 1023;
                    Op[((size_t)(b*Hc + hh)*Tc + t)*ostr + d] = acc[it][jt][r];
                }
            } else {
#pragma unroll
                for (int r = 0; r < 4; r++)
                    Op[(size_t)(mb + r) * DMc + col] = acc[it][jt][r];
            }
        }
    }
}

// ---------------------------------------------------------------------------
// Transpose D: [bh][t][128] f32 -> [bh][128][t] f32
// ---------------------------------------------------------------------------
__global__ __launch_bounds__(256)
void transpose_k(const float* __restrict__ Din, float* __restrict__ DoutT)
{
    __shared__ float tile[32][33];
    const int bh = blockIdx.z;
    const int t0 = blockIdx.x * 32, d0 = blockIdx.y * 32;
    const int tx = threadIdx.x & 31, ty = threadIdx.x >> 5;
    const float* src = Din   + (size_t)bh * TD2;
    float* dst       = DoutT + (size_t)bh * TD2;
#pragma unroll
    for (int i = 0; i < 4; i++)
        tile[ty + 8*i][tx] = src[(size_t)(t0 + ty + 8*i)*128 + d0 + tx];
    __syncthreads();
#pragma unroll
    for (int i = 0; i < 4; i++)
        dst[(size_t)(d0 + ty + 8*i)*Tc + t0 + tx] = tile[tx][ty + 8*i];
}

// ---------------------------------------------------------------------------
// Fused propagation step, SPLIT-bf16 MFMA (hi+lo pairs -> ~f32 precision).
// ---------------------------------------------------------------------------
template<int FINAL>
__global__ __launch_bounds__(256)
void prop_k(const float* __restrict__ Qg, const float* __restrict__ Kg,
            const float* __restrict__ DinT, float* __restrict__ Dout,
            const float* __restrict__ llam)
{
    __shared__ bf16_t Ksh[32*KSTR], Ksl[32*KSTR];   // K chunk [s][dk]
    __shared__ bf16_t Dsh[128*SSTR], Dsl[128*SSTR]; // D chunk [d][s]
    __shared__ bf16_t Psh[128*SSTR], Psl[128*SSTR]; // P chunk [t][s]
    __shared__ float  Lrow[128];

    const int tid = threadIdx.x;
    const int wv  = tid >> 6;
    const int ln  = tid & 63;
    const int l15 = ln & 15;
    const int qd  = ln >> 4;
    const int bh  = blockIdx.y;
    const int T0  = blockIdx.x * 128;

    const float* Qh  = Qg   + (size_t)bh * TD;
    const float* Kh  = Kg   + (size_t)bh * TD;
    const float* DTh = DinT + (size_t)bh * TD2;

    bf16x8 qh[2][2], ql[2][2];
#pragma unroll
    for (int ti = 0; ti < 2; ti++) {
        const float* qp = &Qh[(size_t)(T0 + (2*wv + ti)*16 + l15) * DKc];
#pragma unroll
        for (int ks = 0; ks < 2; ks++) {
            float4 a = *(const float4*)&qp[ks*32 + qd*8];
            float4 b = *(const float4*)&qp[ks*32 + qd*8 + 4];
            float v8[8] = {a.x,a.y,a.z,a.w,b.x,b.y,b.z,b.w};
#pragma unroll
            for (int j = 0; j < 8; j++) {
                qh[ti][ks][j] = (bf16_t)v8[j];
                ql[ti][ks][j] = (bf16_t)(v8[j] - (float)qh[ti][ks][j]);
            }
        }
    }

    f32x4 acc[4][4];
#pragma unroll
    for (int i = 0; i < 4; i++)
#pragma unroll
        for (int j = 0; j < 4; j++) acc[i][j] = (f32x4)0.f;
    float rs[2][4] = {{0.f,0.f,0.f,0.f},{0.f,0.f,0.f,0.f}};

#pragma unroll 1
    for (int ch = 0; ch < 32; ch++) {
        const int s0 = ch * 32;
        __syncthreads();
#pragma unroll
        for (int i = 0; i < 2; i++) {
            int id = tid + i*256;
            int r = id >> 4, c4 = (id & 15) * 4;
            float4 v = *(const float4*)&Kh[(size_t)(s0 + r)*DKc + c4];
            packsplit4(&Ksh[r*KSTR + c4], &Ksl[r*KSTR + c4], v);
        }
#pragma unroll
        for (int i = 0; i < 4; i++) {
            int id = tid + i*256;
            int r = id >> 3, c4 = (id & 7) * 4;
            float4 v = *(const float4*)&DTh[(size_t)r*Tc + s0 + c4];
            packsplit4(&Dsh[r*SSTR + c4], &Dsl[r*SSTR + c4], v);
        }
        __syncthreads();
        f32x4 pacc[2][2];
#pragma unroll
        for (int ti = 0; ti < 2; ti++)
#pragma unroll
            for (int si = 0; si < 2; si++) pacc[ti][si] = (f32x4)0.f;
#pragma unroll
        for (int ks = 0; ks < 2; ks++) {
            bf16x8 kbh[2], kbl[2];
#pragma unroll
            for (int si = 0; si < 2; si++) {
                kbh[si] = ld8(&Ksh[(si*16 + l15)*KSTR + ks*32 + qd*8]);
                kbl[si] = ld8(&Ksl[(si*16 + l15)*KSTR + ks*32 + qd*8]);
            }
#pragma unroll
            for (int ti = 0; ti < 2; ti++)
#pragma unroll
                for (int si = 0; si < 2; si++) {
                    pacc[ti][si] = __builtin_amdgcn_mfma_f32_16x16x32_bf16(
                        qh[ti][ks], kbh[si], pacc[ti][si], 0, 0, 0);
                    pacc[ti][si] = __builtin_amdgcn_mfma_f32_16x16x32_bf16(
                        ql[ti][ks], kbh[si], pacc[ti][si], 0, 0, 0);
                    pacc[ti][si] = __builtin_amdgcn_mfma_f32_16x16x32_bf16(
                        qh[ti][ks], kbl[si], pacc[ti][si], 0, 0, 0);
                }
        }
#pragma unroll
        for (int ti = 0; ti < 2; ti++)
#pragma unroll
            for (int si = 0; si < 2; si++)
#pragma unroll
                for (int r = 0; r < 4; r++) {
                    float e = __expf(pacc[ti][si][r] * 0.125f);
                    rs[ti][r] += e;
                    int t = (2*wv + ti)*16 + qd*4 + r;
                    int s = si*16 + l15;
                    bf16_t eh = (bf16_t)e;
                    Psh[t*SSTR + s] = eh;
                    Psl[t*SSTR + s] = (bf16_t)(e - (float)eh);
                }
        __syncthreads();
        bf16x8 adh[4], adl[4], pbh[4], pbl[4];
#pragma unroll
        for (int it = 0; it < 4; it++) {
            int row = ((wv>>1)*64 + it*16 + l15)*SSTR + qd*8;
            adh[it] = ld8(&Dsh[row]);
            adl[it] = ld8(&Dsl[row]);
        }
#pragma unroll
        for (int jt = 0; jt < 4; jt++) {
            int row = ((wv&1)*64 + jt*16 + l15)*SSTR + qd*8;
            pbh[jt] = ld8(&Psh[row]);
            pbl[jt] = ld8(&Psl[row]);
        }
#pragma unroll
        for (int it = 0; it < 4; it++)
#pragma unroll
            for (int jt = 0; jt < 4; jt++) {
                acc[it][jt] = __builtin_amdgcn_mfma_f32_16x16x32_bf16(
                    adh[it], pbh[jt], acc[it][jt], 0, 0, 0);
                acc[it][jt] = __builtin_amdgcn_mfma_f32_16x16x32_bf16(
                    adh[it], pbl[jt], acc[it][jt], 0, 0, 0);
                acc[it][jt] = __builtin_amdgcn_mfma_f32_16x16x32_bf16(
                    adl[it], pbh[jt], acc[it][jt], 0, 0, 0);
            }
    }

#pragma unroll
    for (int ti = 0; ti < 2; ti++)
#pragma unroll
        for (int r = 0; r < 4; r++) {
            float v = rs[ti][r];
            v += __shfl_xor(v, 1);  v += __shfl_xor(v, 2);
            v += __shfl_xor(v, 4);  v += __shfl_xor(v, 8);
            rs[ti][r] = v;
        }
    __syncthreads();
    if (l15 == 0) {
#pragma unroll
        for (int ti = 0; ti < 2; ti++)
#pragma unroll
            for (int r = 0; r < 4; r++)
                Lrow[(2*wv + ti)*16 + qd*4 + r] = rs[ti][r];
    }
    __syncthreads();

    const float lam = 1.f / (1.f + __expf(-llam[0]));
    const float oml = 1.f - lam;

#pragma unroll
    for (int jt = 0; jt < 4; jt++) {
        const int t = (wv&1)*64 + jt*16 + l15;
        const float s = lam / Lrow[t];
#pragma unroll
        for (int it = 0; it < 4; it++) {
            const int d0 = (wv>>1)*64 + it*16 + qd*4;
            float v[4];
#pragma unroll
            for (int r = 0; r < 4; r++) {
                float res = DTh[(size_t)(d0 + r)*Tc + T0 + t];
                v[r] = oml*res + s*acc[it][jt][r];
            }
            if (FINAL) {
                *(float4*)&Dout[((size_t)bh*Tc + T0 + t)*128 + d0] =
                    make_float4(v[0], v[1], v[2], v[3]);
            } else {
#pragma unroll
                for (int r = 0; r < 4; r++)
                    Dout[((size_t)bh*128 + d0 + r)*Tc + T0 + t] = v[r];
            }
        }
    }
}

// ---------------------------------------------------------------------------
// mean over T per (b,h,d)  — D in combined [bh][t][128] layout
// ---------------------------------------------------------------------------
__global__ __launch_bounds__(256)
void mean_k(const float* __restrict__ D,
            float* __restrict__ Mre, float* __restrict__ Mim)
{
    __shared__ float sre[4][64], sim[4][64];
    const int bh = blockIdx.x;
    const int d = threadIdx.x & 63, q = threadIdx.x >> 6;
    const float* p = D + (size_t)bh * TD2;
    float ar = 0.f, ai = 0.f;
    for (int t = q*256; t < q*256 + 256; t++) {
        ar += p[t*128 + d]; ai += p[t*128 + 64 + d];
    }
    sre[q][d] = ar; sim[q][d] = ai;
    __syncthreads();
    if (threadIdx.x < 64) {
        float r  = sre[0][d]+sre[1][d]+sre[2][d]+sre[3][d];
        float im = sim[0][d]+sim[1][d]+sim[2][d]+sim[3][d];
        Mre[bh*64 + d] = r  * (1.f/1024.f);
        Mim[bh*64 + d] = im * (1.f/1024.f);
    }
}

// ---------------------------------------------------------------------------
// gate softmax over T + value gating; gateV emitted as bf16 hi/lo pair
// ---------------------------------------------------------------------------
__global__ __launch_bounds__(256)
void gate_k(const float* __restrict__ D,
            const float* __restrict__ Mre, const float* __restrict__ Mim,
            const float* __restrict__ V,
            float* __restrict__ gate_out,
            bf16_t* __restrict__ gVh, bf16_t* __restrict__ gVl)
{
    __shared__ float part[4][64];
    __shared__ float dinv[64];
    const int bh = blockIdx.x;
    const int d = threadIdx.x & 63, q = threadIdx.x >> 6;
    const float* p = D + (size_t)bh * TD2;
    const float mre = Mre[bh*64 + d], mim = Mim[bh*64 + d];
    const float mabs = sqrtf(mre*mre + mim*mim);

    float ps = 0.f;
    for (int t = q*256; t < (q+1)*256; t++) {
        float dr = p[t*128 + d], dv = p[t*128 + 64 + d];
        float c = (dr*mre + dv*mim) / (sqrtf(dr*dr + dv*dv)*mabs + 1e-8f);
        ps += __expf(c);
    }
    part[q][d] = ps;
    __syncthreads();
    if (threadIdx.x < 64)
        dinv[d] = 1.f / (part[0][d]+part[1][d]+part[2][d]+part[3][d]);
    __syncthreads();

    const float di_ = dinv[d];
    const int b = bh >> 4, hh = bh & 15;
    const float* pv = V + (size_t)bh * TD;
    for (int t = q*256; t < (q+1)*256; t++) {
        float dr = p[t*128 + d], dv = p[t*128 + 64 + d];
        float c = (dr*mre + dv*mim) / (sqrtf(dr*dr + dv*dv)*mabs + 1e-8f);
        float g = __expf(c) * di_;
        gate_out[(size_t)bh*TD + t*64 + d] = g;
        float gv = g * pv[t*64 + d];
        size_t o = ((size_t)b*Tc + t)*DMc + hh*64 + d;
        bf16_t gh = (bf16_t)gv;
        gVh[o] = gh;
        gVl[o] = (bf16_t)(gv - (float)gh);
    }
}

// ---------------------------------------------------------------------------
extern "C" void kernel_launch(void* const* d_in, const int* in_sizes, int n_in,
                              void* d_out, int out_size, void* d_ws, size_t ws_size,
                              hipStream_t stream)
{
    const float* x    = (const float*)d_in[0];
    const float* W_Q  = (const float*)d_in[1];
    const float* W_K  = (const float*)d_in[2];
    const float* W_re = (const float*)d_in[3];
    const float* W_im = (const float*)d_in[4];
    const float* W_V  = (const float*)d_in[5];
    const float* W_O  = (const float*)d_in[6];
    const float* llam = (const float*)d_in[7];

    float* out      = (float*)d_out;
    float* gate_out = out + (size_t)Mc * DMc;

    float* ws = (float*)d_ws;
    const size_t S = (size_t)BHc * TD;   // 4M floats
    float* Q    = ws;                    // 16 MB
    float* K    = ws + S;                // 16 MB
    float* V    = ws + 2*S;              // 16 MB
    float* Dc   = ws + 3*S;              // 32 MB  combined [bh][t][128]
    float* DT0  = ws + 5*S;              // 32 MB  [bh][128][t]
    float* DT1  = ws + 7*S;              // 32 MB
    float* Mre  = ws + 9*S;
    float* Mim  = Mre + BHc*DKc;
    bf16_t* xh  = (bf16_t*)(ws + 9*S + 8192);  // 8 MB
    bf16_t* xl  = xh + (size_t)Mc * DMc;       // 8 MB
    bf16_t* WT  = xl + (size_t)Mc * DMc;       // 6 x 4 MB (hi+lo per weight)
    bf16_t* gVh = xh;                          // alias: x dead after mgemm<0>
    bf16_t* gVl = xl;

    convx_k<<<4096, 256, 0, stream>>>(x, xh, xl);
    convw_k<<<dim3(32, 32, 6), 256, 0, stream>>>(
        W_Q, W_K, W_re, W_im, W_V, W_O, WT);

    // projections: Q,K -> slabs; Dre/Dim -> combined Dc; V -> slab
    mgemm_k<0><<<dim3(32, 40), 256, 0, stream>>>(
        xh, xl, WT, Q, K, Dc, Dc + 64, V);

    transpose_k<<<dim3(32, 4, 64), 256, 0, stream>>>(Dc, DT0);

    prop_k<0><<<dim3(8, 64), 256, 0, stream>>>(Q, K, DT0, DT1, llam);
    prop_k<0><<<dim3(8, 64), 256, 0, stream>>>(Q, K, DT1, DT0, llam);
    prop_k<1><<<dim3(8, 64), 256, 0, stream>>>(Q, K, DT0, Dc, llam);

    mean_k<<<64, 256, 0, stream>>>(Dc, Mre, Mim);
    gate_k<<<64, 256, 0, stream>>>(Dc, Mre, Mim, V, gate_out, gVh, gVl);

    mgemm_k<1><<<dim3(32, 8), 256, 0, stream>>>(
        gVh, gVl, WT, out, out, out, out, out);
}

// Round 5
// 816.170 us; speedup vs baseline: 2.9601x; 1.0246x over previous
//
#include <hip/hip_runtime.h>
#include <math.h>

// Problem constants
#define Bc 4
#define Tc 1024
#define DMc 1024
#define Hc 16
#define DKc 64
#define BHc 64          // B*H
#define Mc 4096         // B*T
#define TD (Tc*DKc)     // 65536 el per (b,h) slab, stride-64 layout
#define TD2 (Tc*128)    // combined re|im slab, stride-128 layout
#define TDS (128*2048)  // split-D slab: [d(128)][s hi 1024 | s lo 1024] bf16

typedef __bf16 bf16_t;
typedef bf16_t bf16x4 __attribute__((ext_vector_type(4)));
typedef bf16_t bf16x8 __attribute__((ext_vector_type(8)));
typedef float  f32x4  __attribute__((ext_vector_type(4)));

#define KSTR 68   // prop_k: LDS stride for 64-wide rows (bf16)
#define SSTR 36   // prop_k: LDS stride for 32-wide rows (bf16)
#define GSTR 40   // mgemm: LDS stride for 32-wide rows (80 B)

__device__ __forceinline__ bf16x8 ld8(const bf16_t* p) {
    union { bf16x8 v; struct { bf16x4 a, b; } s; } u;
    u.s.a = *(const bf16x4*)p;
    u.s.b = *(const bf16x4*)(p + 4);
    return u.v;
}
__device__ __forceinline__ void packsplit4(bf16_t* dh, bf16_t* dl, float4 v) {
    bf16x4 h, l;
    h[0]=(bf16_t)v.x; l[0]=(bf16_t)(v.x-(float)h[0]);
    h[1]=(bf16_t)v.y; l[1]=(bf16_t)(v.y-(float)h[1]);
    h[2]=(bf16_t)v.z; l[2]=(bf16_t)(v.z-(float)h[2]);
    h[3]=(bf16_t)v.w; l[3]=(bf16_t)(v.w-(float)h[3]);
    *(bf16x4*)dh = h; *(bf16x4*)dl = l;
}

// ---------------------------------------------------------------------------
// Convert x (4096x1024 f32) -> xh, xl bf16
// ---------------------------------------------------------------------------
__global__ __launch_bounds__(256)
void convx_k(const float* __restrict__ x,
             bf16_t* __restrict__ xh, bf16_t* __restrict__ xl)
{
    size_t i = ((size_t)blockIdx.x * 256 + threadIdx.x) * 4;
    float4 v = *(const float4*)&x[i];
    packsplit4(&xh[i], &xl[i], v);
}

// ---------------------------------------------------------------------------
// Convert + transpose each W (1024x1024 f32 [k][n]) -> WT hi/lo bf16 [n][k].
// ---------------------------------------------------------------------------
__global__ __launch_bounds__(256)
void convw_k(const float* __restrict__ W0, const float* __restrict__ W1,
             const float* __restrict__ W2, const float* __restrict__ W3,
             const float* __restrict__ W4, const float* __restrict__ W5,
             bf16_t* __restrict__ WT)
{
    __shared__ float tile[32][33];
    const float* Ws[6] = {W0, W1, W2, W3, W4, W5};
    const int wi = blockIdx.z;
    const float* W = Ws[wi];
    bf16_t* WTh = WT + (size_t)wi * 2097152;
    bf16_t* WTl = WTh + 1048576;

    const int tx = threadIdx.x & 31, ty = threadIdx.x >> 5;
    const int k0 = blockIdx.x * 32, n0 = blockIdx.y * 32;
#pragma unroll
    for (int i = 0; i < 4; i++)
        tile[ty + 8*i][tx] = W[(size_t)(k0 + ty + 8*i) * DMc + n0 + tx];
    __syncthreads();
    const int kg = threadIdx.x & 7, n = threadIdx.x >> 3;
    float4 v = make_float4(tile[kg*4+0][n], tile[kg*4+1][n],
                           tile[kg*4+2][n], tile[kg*4+3][n]);
    const size_t o = (size_t)(n0 + n) * DMc + k0 + kg*4;
    packsplit4(&WTh[o], &WTl[o], v);
}

// ---------------------------------------------------------------------------
// Split-bf16 MFMA GEMM (3 products, f32 accum). A [m][k] hi/lo; B = WT [n][k].
// MODE 0: sel 0->Qs split slab [bh][t][128]; 1->Ks split slab;
//         2,3 -> Dc f32 [bh][t][128] (col 0 / 64); 4 -> V f32 [bh][t][64].
// MODE 1: row-major f32 out (weight 5 = W_O).
// ---------------------------------------------------------------------------
template<int MODE>
__global__ __launch_bounds__(256)
void mgemm_k(const bf16_t* __restrict__ Ah, const bf16_t* __restrict__ Al,
             const bf16_t* __restrict__ WT,
             bf16_t* __restrict__ Oq, bf16_t* __restrict__ Ok,
             float* __restrict__ Od, float* __restrict__ Ov,
             float* __restrict__ Of)
{
    __shared__ bf16_t Ash[128*GSTR], Asl[128*GSTR];
    __shared__ bf16_t Bsh[128*GSTR], Bsl[128*GSTR];

    const int tid = threadIdx.x;
    const int wv  = tid >> 6;
    const int ln  = tid & 63;
    const int l15 = ln & 15;
    const int qd  = ln >> 4;
    const int m0  = blockIdx.x * 128;
    const int by  = blockIdx.y;

    const bf16_t *Bh, *Bl;
    int n0, sel;
    if (MODE == 0) {
        sel = by >> 3;
        n0 = (by & 7) * 128;
        Bh = WT + (size_t)sel * 2097152;
        Bl = Bh + 1048576;
    } else {
        sel = 5;
        Bh = WT + (size_t)5 * 2097152;
        Bl = Bh + 1048576;
        n0 = by * 128;
    }

    const int srow  = tid >> 1;
    const int shalf = (tid & 1) * 16;

    f32x4 acc[4][4];
#pragma unroll
    for (int i = 0; i < 4; i++)
#pragma unroll
        for (int j = 0; j < 4; j++) acc[i][j] = (f32x4)0.f;

#pragma unroll 1
    for (int kt = 0; kt < DMc; kt += 32) {
        __syncthreads();
        {
            const size_t ga = (size_t)(m0 + srow) * DMc + kt + shalf;
            bf16x8 a0 = *(const bf16x8*)&Ah[ga];
            bf16x8 a1 = *(const bf16x8*)&Ah[ga + 8];
            bf16x8 a2 = *(const bf16x8*)&Al[ga];
            bf16x8 a3 = *(const bf16x8*)&Al[ga + 8];
            const size_t gb = (size_t)(n0 + srow) * DMc + kt + shalf;
            bf16x8 b0 = *(const bf16x8*)&Bh[gb];
            bf16x8 b1 = *(const bf16x8*)&Bh[gb + 8];
            bf16x8 b2 = *(const bf16x8*)&Bl[gb];
            bf16x8 b3 = *(const bf16x8*)&Bl[gb + 8];
            const int lo = srow * GSTR + shalf;
            *(bf16x8*)&Ash[lo]     = a0;
            *(bf16x8*)&Ash[lo + 8] = a1;
            *(bf16x8*)&Asl[lo]     = a2;
            *(bf16x8*)&Asl[lo + 8] = a3;
            *(bf16x8*)&Bsh[lo]     = b0;
            *(bf16x8*)&Bsh[lo + 8] = b1;
            *(bf16x8*)&Bsl[lo]     = b2;
            *(bf16x8*)&Bsl[lo + 8] = b3;
        }
        __syncthreads();

        bf16x8 fah[4], fal[4], fbh[4], fbl[4];
#pragma unroll
        for (int it = 0; it < 4; it++) {
            const int row = ((wv>>1)*64 + it*16 + l15) * GSTR + qd*8;
            fah[it] = ld8(&Ash[row]);
            fal[it] = ld8(&Asl[row]);
        }
#pragma unroll
        for (int jt = 0; jt < 4; jt++) {
            const int row = ((wv&1)*64 + jt*16 + l15) * GSTR + qd*8;
            fbh[jt] = ld8(&Bsh[row]);
            fbl[jt] = ld8(&Bsl[row]);
        }
#pragma unroll
        for (int it = 0; it < 4; it++)
#pragma unroll
            for (int jt = 0; jt < 4; jt++) {
                acc[it][jt] = __builtin_amdgcn_mfma_f32_16x16x32_bf16(
                    fah[it], fbh[jt], acc[it][jt], 0, 0, 0);
                acc[it][jt] = __builtin_amdgcn_mfma_f32_16x16x32_bf16(
                    fah[it], fbl[jt], acc[it][jt], 0, 0, 0);
                acc[it][jt] = __builtin_amdgcn_mfma_f32_16x16x32_bf16(
                    fal[it], fbh[jt], acc[it][jt], 0, 0, 0);
            }
    }

#pragma unroll
    for (int it = 0; it < 4; it++) {
        const int mb = m0 + (wv>>1)*64 + it*16 + qd*4;
#pragma unroll
        for (int jt = 0; jt < 4; jt++) {
            const int col = n0 + (wv&1)*64 + jt*16 + l15;
            if (MODE == 0) {
                const int hh = col >> 6, d = col & 63;
#pragma unroll
                for (int r = 0; r < 4; r++) {
                    const int m = mb + r;
                    const int b = m >> 10, t = m & 1023;
                    const float val = acc[it][jt][r];
                    if (sel <= 1) {
                        bf16_t* O = sel ? Ok : Oq;
                        const size_t o = ((size_t)(b*Hc + hh)*Tc + t)*128 + d;
                        bf16_t vh = (bf16_t)val;
                        O[o]      = vh;
                        O[o + 64] = (bf16_t)(val - (float)vh);
                    } else if (sel <= 3) {
                        Od[((size_t)(b*Hc + hh)*Tc + t)*128 + (sel==3?64:0) + d] = val;
                    } else {
                        Ov[((size_t)(b*Hc + hh)*Tc + t)*64 + d] = val;
                    }
                }
            } else {
#pragma unroll
                for (int r = 0; r < 4; r++)
                    Of[(size_t)(mb + r) * DMc + col] = acc[it][jt][r];
            }
        }
    }
}

// ---------------------------------------------------------------------------
// Transpose + split: Dc f32 [bh][t][128] -> DT bf16 [bh][d(128)][hi s | lo s]
// ---------------------------------------------------------------------------
__global__ __launch_bounds__(256)
void transpose_k(const float* __restrict__ Din, bf16_t* __restrict__ DT)
{
    __shared__ float tile[32][33];
    const int bh = blockIdx.z;
    const int t0 = blockIdx.x * 32, d0 = blockIdx.y * 32;
    const int tx = threadIdx.x & 31, ty = threadIdx.x >> 5;
    const float* src = Din + (size_t)bh * TD2;
    bf16_t* dst      = DT  + (size_t)bh * TDS;
#pragma unroll
    for (int i = 0; i < 4; i++)
        tile[ty + 8*i][tx] = src[(size_t)(t0 + ty + 8*i)*128 + d0 + tx];
    __syncthreads();
#pragma unroll
    for (int i = 0; i < 4; i++) {
        float v = tile[tx][ty + 8*i];
        const size_t o = (size_t)(d0 + ty + 8*i)*2048 + t0 + tx;
        bf16_t h = (bf16_t)v;
        dst[o]        = h;
        dst[o + 1024] = (bf16_t)(v - (float)h);
    }
}

// ---------------------------------------------------------------------------
// Fused propagation step, split-bf16 MFMA, pre-split inputs, double-buffered
// K/D staging (load-early / ds_write-late), 2 barriers per 32-s chunk.
// Q/K: bf16 [bh][t|s][hi 64 | lo 64].  Din: split-D slab.
// FINAL=0: out = split-D slab.  FINAL=1: out = Dc f32 [bh][t][128].
// Grid (x=bh, y=t-tile) so same-bh tiles share an XCD (id % 8 == bh % 8).
// ---------------------------------------------------------------------------
template<int FINAL>
__global__ __launch_bounds__(256)
void prop_k(const bf16_t* __restrict__ Qg, const bf16_t* __restrict__ Kg,
            const bf16_t* __restrict__ DTin, bf16_t* __restrict__ DTout,
            float* __restrict__ Dc, const float* __restrict__ llam)
{
    __shared__ bf16_t Ksh[2][32*KSTR], Ksl[2][32*KSTR];
    __shared__ bf16_t Dsh[2][128*SSTR], Dsl[2][128*SSTR];
    __shared__ bf16_t Psh[128*SSTR], Psl[128*SSTR];
    __shared__ float  Lrow[128];

    const int tid = threadIdx.x;
    const int wv  = tid >> 6;
    const int ln  = tid & 63;
    const int l15 = ln & 15;
    const int qd  = ln >> 4;
    const int bh  = blockIdx.x;
    const int T0  = blockIdx.y * 128;

    const bf16_t* Qh  = Qg   + (size_t)bh * (Tc*128);
    const bf16_t* Kh  = Kg   + (size_t)bh * (Tc*128);
    const bf16_t* DTh = DTin + (size_t)bh * TDS;

    // Q fragments (registers, loop-invariant)
    bf16x8 qh[2][2], ql[2][2];
#pragma unroll
    for (int ti = 0; ti < 2; ti++) {
        const bf16_t* qp = &Qh[(size_t)(T0 + (2*wv + ti)*16 + l15) * 128];
#pragma unroll
        for (int ks = 0; ks < 2; ks++) {
            qh[ti][ks] = *(const bf16x8*)&qp[ks*32 + qd*8];
            ql[ti][ks] = *(const bf16x8*)&qp[64 + ks*32 + qd*8];
        }
    }

    f32x4 acc[4][4];
#pragma unroll
    for (int i = 0; i < 4; i++)
#pragma unroll
        for (int j = 0; j < 4; j++) acc[i][j] = (f32x4)0.f;
    float rs[2][4] = {{0.f,0.f,0.f,0.f},{0.f,0.f,0.f,0.f}};

    bf16x8 kr[2], dr[4];
    // prologue: stage chunk 0 into buf 0
#pragma unroll
    for (int i = 0; i < 2; i++) {
        int id = tid + i*256;
        kr[i] = *(const bf16x8*)&Kh[(size_t)(id>>4)*128 + (id&15)*8];
    }
#pragma unroll
    for (int i = 0; i < 4; i++) {
        int id = tid + i*256;
        dr[i] = *(const bf16x8*)&DTh[(size_t)(id>>3)*2048 + ((id>>2)&1)*1024 + (id&3)*8];
    }
#pragma unroll
    for (int i = 0; i < 2; i++) {
        int id = tid + i*256;
        int row = id>>4, seg = id&15;
        bf16_t* p = (seg < 8) ? &Ksh[0][row*KSTR + (seg&7)*8]
                              : &Ksl[0][row*KSTR + (seg&7)*8];
        *(bf16x8*)p = kr[i];
    }
#pragma unroll
    for (int i = 0; i < 4; i++) {
        int id = tid + i*256;
        int row = id>>3, seg = id&7;
        bf16_t* p = (seg < 4) ? &Dsh[0][row*SSTR + (seg&3)*8]
                              : &Dsl[0][row*SSTR + (seg&3)*8];
        *(bf16x8*)p = dr[i];
    }
    __syncthreads();

#pragma unroll 1
    for (int ch = 0; ch < 32; ch++) {
        const int b = ch & 1;
        // ---- issue next chunk's global loads (consumed after exp phase)
        if (ch < 31) {
            const int s0 = (ch + 1) * 32;
#pragma unroll
            for (int i = 0; i < 2; i++) {
                int id = tid + i*256;
                kr[i] = *(const bf16x8*)&Kh[(size_t)(s0 + (id>>4))*128 + (id&15)*8];
            }
#pragma unroll
            for (int i = 0; i < 4; i++) {
                int id = tid + i*256;
                dr[i] = *(const bf16x8*)&DTh[(size_t)(id>>3)*2048 + ((id>>2)&1)*1024
                                             + s0 + (id&3)*8];
            }
        }
        // ---- score phase: t-tiles {2wv,2wv+1} x s-tiles {0,1}
        f32x4 pacc[2][2];
#pragma unroll
        for (int ti = 0; ti < 2; ti++)
#pragma unroll
            for (int si = 0; si < 2; si++) pacc[ti][si] = (f32x4)0.f;
#pragma unroll
        for (int ks = 0; ks < 2; ks++) {
            bf16x8 kbh[2], kbl[2];
#pragma unroll
            for (int si = 0; si < 2; si++) {
                kbh[si] = ld8(&Ksh[b][(si*16 + l15)*KSTR + ks*32 + qd*8]);
                kbl[si] = ld8(&Ksl[b][(si*16 + l15)*KSTR + ks*32 + qd*8]);
            }
#pragma unroll
            for (int ti = 0; ti < 2; ti++)
#pragma unroll
                for (int si = 0; si < 2; si++) {
                    pacc[ti][si] = __builtin_amdgcn_mfma_f32_16x16x32_bf16(
                        qh[ti][ks], kbh[si], pacc[ti][si], 0, 0, 0);
                    pacc[ti][si] = __builtin_amdgcn_mfma_f32_16x16x32_bf16(
                        ql[ti][ks], kbh[si], pacc[ti][si], 0, 0, 0);
                    pacc[ti][si] = __builtin_amdgcn_mfma_f32_16x16x32_bf16(
                        qh[ti][ks], kbl[si], pacc[ti][si], 0, 0, 0);
                }
        }
        // ---- exp + split-store P + row-sum accum
#pragma unroll
        for (int ti = 0; ti < 2; ti++)
#pragma unroll
            for (int si = 0; si < 2; si++)
#pragma unroll
                for (int r = 0; r < 4; r++) {
                    float e = __expf(pacc[ti][si][r] * 0.125f);
                    rs[ti][r] += e;
                    int t = (2*wv + ti)*16 + qd*4 + r;
                    int s = si*16 + l15;
                    bf16_t eh = (bf16_t)e;
                    Psh[t*SSTR + s] = eh;
                    Psl[t*SSTR + s] = (bf16_t)(e - (float)eh);
                }
        // ---- commit next chunk's staging into the other buffer
        if (ch < 31) {
            const int nb = b ^ 1;
#pragma unroll
            for (int i = 0; i < 2; i++) {
                int id = tid + i*256;
                int row = id>>4, seg = id&15;
                bf16_t* p = (seg < 8) ? &Ksh[nb][row*KSTR + (seg&7)*8]
                                      : &Ksl[nb][row*KSTR + (seg&7)*8];
                *(bf16x8*)p = kr[i];
            }
#pragma unroll
            for (int i = 0; i < 4; i++) {
                int id = tid + i*256;
                int row = id>>3, seg = id&7;
                bf16_t* p = (seg < 4) ? &Dsh[nb][row*SSTR + (seg&3)*8]
                                      : &Dsl[nb][row*SSTR + (seg&3)*8];
                *(bf16x8*)p = dr[i];
            }
        }
        __syncthreads();   // Ps (and staged next bufs) visible
        // ---- main phase: acc[d][t] += D(chunk) x P, K=32
        bf16x8 adh[4], adl[4], pbh[4], pbl[4];
#pragma unroll
        for (int it = 0; it < 4; it++) {
            int row = ((wv>>1)*64 + it*16 + l15)*SSTR + qd*8;
            adh[it] = ld8(&Dsh[b][row]);
            adl[it] = ld8(&Dsl[b][row]);
        }
#pragma unroll
        for (int jt = 0; jt < 4; jt++) {
            int row = ((wv&1)*64 + jt*16 + l15)*SSTR + qd*8;
            pbh[jt] = ld8(&Psh[row]);
            pbl[jt] = ld8(&Psl[row]);
        }
#pragma unroll
        for (int it = 0; it < 4; it++)
#pragma unroll
            for (int jt = 0; jt < 4; jt++) {
                acc[it][jt] = __builtin_amdgcn_mfma_f32_16x16x32_bf16(
                    adh[it], pbh[jt], acc[it][jt], 0, 0, 0);
                acc[it][jt] = __builtin_amdgcn_mfma_f32_16x16x32_bf16(
                    adh[it], pbl[jt], acc[it][jt], 0, 0, 0);
                acc[it][jt] = __builtin_amdgcn_mfma_f32_16x16x32_bf16(
                    adl[it], pbh[jt], acc[it][jt], 0, 0, 0);
            }
        __syncthreads();   // chunk fully consumed
    }

    // ---- row-sum reduce (across l15 = lane bits 0..3)
#pragma unroll
    for (int ti = 0; ti < 2; ti++)
#pragma unroll
        for (int r = 0; r < 4; r++) {
            float v = rs[ti][r];
            v += __shfl_xor(v, 1);  v += __shfl_xor(v, 2);
            v += __shfl_xor(v, 4);  v += __shfl_xor(v, 8);
            rs[ti][r] = v;
        }
    if (l15 == 0) {
#pragma unroll
        for (int ti = 0; ti < 2; ti++)
#pragma unroll
            for (int r = 0; r < 4; r++)
                Lrow[(2*wv + ti)*16 + qd*4 + r] = rs[ti][r];
    }
    __syncthreads();

    const float lam = 1.f / (1.f + __expf(-llam[0]));
    const float oml = 1.f - lam;
    bf16_t* DToutg = (FINAL ? (bf16_t*)nullptr : DTout + (size_t)bh * TDS);

#pragma unroll
    for (int jt = 0; jt < 4; jt++) {
        const int t = (wv&1)*64 + jt*16 + l15;
        const float s = lam / Lrow[t];
#pragma unroll
        for (int it = 0; it < 4; it++) {
            const int d0 = (wv>>1)*64 + it*16 + qd*4;
            float v[4];
#pragma unroll
            for (int r = 0; r < 4; r++) {
                const size_t ro = (size_t)(d0 + r)*2048 + T0 + t;
                float res = (float)DTh[ro] + (float)DTh[ro + 1024];
                v[r] = oml*res + s*acc[it][jt][r];
            }
            if (FINAL) {
                *(float4*)&Dc[((size_t)bh*Tc + T0 + t)*128 + d0] =
                    make_float4(v[0], v[1], v[2], v[3]);
            } else {
#pragma unroll
                for (int r = 0; r < 4; r++) {
                    const size_t ro = (size_t)(d0 + r)*2048 + T0 + t;
                    bf16_t h = (bf16_t)v[r];
                    DToutg[ro]        = h;
                    DToutg[ro + 1024] = (bf16_t)(v[r] - (float)h);
                }
            }
        }
    }
}

// ---------------------------------------------------------------------------
// mean over T per (b,h,d)  — D in combined [bh][t][128] f32 layout
// ---------------------------------------------------------------------------
__global__ __launch_bounds__(256)
void mean_k(const float* __restrict__ D,
            float* __restrict__ Mre, float* __restrict__ Mim)
{
    __shared__ float sre[4][64], sim[4][64];
    const int bh = blockIdx.x;
    const int d = threadIdx.x & 63, q = threadIdx.x >> 6;
    const float* p = D + (size_t)bh * TD2;
    float ar = 0.f, ai = 0.f;
    for (int t = q*256; t < q*256 + 256; t++) {
        ar += p[t*128 + d]; ai += p[t*128 + 64 + d];
    }
    sre[q][d] = ar; sim[q][d] = ai;
    __syncthreads();
    if (threadIdx.x < 64) {
        float r  = sre[0][d]+sre[1][d]+sre[2][d]+sre[3][d];
        float im = sim[0][d]+sim[1][d]+sim[2][d]+sim[3][d];
        Mre[bh*64 + d] = r  * (1.f/1024.f);
        Mim[bh*64 + d] = im * (1.f/1024.f);
    }
}

// ---------------------------------------------------------------------------
// gate softmax over T + value gating; gateV emitted as bf16 hi/lo pair
// ---------------------------------------------------------------------------
__global__ __launch_bounds__(256)
void gate_k(const float* __restrict__ D,
            const float* __restrict__ Mre, const float* __restrict__ Mim,
            const float* __restrict__ V,
            float* __restrict__ gate_out,
            bf16_t* __restrict__ gVh, bf16_t* __restrict__ gVl)
{
    __shared__ float part[4][64];
    __shared__ float dinv[64];
    const int bh = blockIdx.x;
    const int d = threadIdx.x & 63, q = threadIdx.x >> 6;
    const float* p = D + (size_t)bh * TD2;
    const float mre = Mre[bh*64 + d], mim = Mim[bh*64 + d];
    const float mabs = sqrtf(mre*mre + mim*mim);

    float ps = 0.f;
    for (int t = q*256; t < (q+1)*256; t++) {
        float dr = p[t*128 + d], dv = p[t*128 + 64 + d];
        float c = (dr*mre + dv*mim) / (sqrtf(dr*dr + dv*dv)*mabs + 1e-8f);
        ps += __expf(c);
    }
    part[q][d] = ps;
    __syncthreads();
    if (threadIdx.x < 64)
        dinv[d] = 1.f / (part[0][d]+part[1][d]+part[2][d]+part[3][d]);
    __syncthreads();

    const float di_ = dinv[d];
    const int b = bh >> 4, hh = bh & 15;
    const float* pv = V + (size_t)bh * TD;
    for (int t = q*256; t < (q+1)*256; t++) {
        float dr = p[t*128 + d], dv = p[t*128 + 64 + d];
        float c = (dr*mre + dv*mim) / (sqrtf(dr*dr + dv*dv)*mabs + 1e-8f);
        float g = __expf(c) * di_;
        gate_out[(size_t)bh*TD + t*64 + d] = g;
        float gv = g * pv[t*64 + d];
        size_t o = ((size_t)b*Tc + t)*DMc + hh*64 + d;
        bf16_t gh = (bf16_t)gv;
        gVh[o] = gh;
        gVl[o] = (bf16_t)(gv - (float)gh);
    }
}

// ---------------------------------------------------------------------------
extern "C" void kernel_launch(void* const* d_in, const int* in_sizes, int n_in,
                              void* d_out, int out_size, void* d_ws, size_t ws_size,
                              hipStream_t stream)
{
    const float* x    = (const float*)d_in[0];
    const float* W_Q  = (const float*)d_in[1];
    const float* W_K  = (const float*)d_in[2];
    const float* W_re = (const float*)d_in[3];
    const float* W_im = (const float*)d_in[4];
    const float* W_V  = (const float*)d_in[5];
    const float* W_O  = (const float*)d_in[6];
    const float* llam = (const float*)d_in[7];

    float* out      = (float*)d_out;
    float* gate_out = out + (size_t)Mc * DMc;

    float* ws = (float*)d_ws;
    const size_t M1 = 1024*1024;
    float*  Dc  = ws;                          // 8M f32 (32 MB) — aliases DT1
    bf16_t* DT1 = (bf16_t*)ws;                 // 16M bf16
    bf16_t* DT0 = (bf16_t*)(ws + 8*M1);        // 16M bf16 (32 MB)
    float*  V   = ws + 16*M1;                  // 4M f32 (16 MB)
    bf16_t* Qs  = (bf16_t*)(ws + 20*M1);       // 8M bf16 (16 MB)
    bf16_t* Ksb = (bf16_t*)(ws + 24*M1);       // 8M bf16 (16 MB)
    float*  Mre = ws + 28*M1;
    float*  Mim = Mre + 4096;
    bf16_t* xh  = (bf16_t*)(ws + 28*M1 + 8192);// 4M bf16 (8 MB)
    bf16_t* xl  = xh + 4*M1;                   // 8 MB
    bf16_t* WT  = xl + 4*M1;                   // 12M bf16 (24 MB)
    bf16_t* gVh = xh;                          // alias: x dead after mgemm<0>
    bf16_t* gVl = xl;

    convx_k<<<4096, 256, 0, stream>>>(x, xh, xl);
    convw_k<<<dim3(32, 32, 6), 256, 0, stream>>>(
        W_Q, W_K, W_re, W_im, W_V, W_O, WT);

    // projections: Q,K -> split slabs; Dre/Dim -> Dc f32; V -> f32 slab
    mgemm_k<0><<<dim3(32, 40), 256, 0, stream>>>(
        xh, xl, WT, Qs, Ksb, Dc, V, nullptr);

    transpose_k<<<dim3(32, 4, 64), 256, 0, stream>>>(Dc, DT0);

    prop_k<0><<<dim3(64, 8), 256, 0, stream>>>(Qs, Ksb, DT0, DT1, nullptr, llam);
    prop_k<0><<<dim3(64, 8), 256, 0, stream>>>(Qs, Ksb, DT1, DT0, nullptr, llam);
    prop_k<1><<<dim3(64, 8), 256, 0, stream>>>(Qs, Ksb, DT0, nullptr, Dc, llam);

    mean_k<<<64, 256, 0, stream>>>(Dc, Mre, Mim);
    gate_k<<<64, 256, 0, stream>>>(Dc, Mre, Mim, V, gate_out, gVh, gVl);

    mgemm_k<1><<<dim3(32, 8), 256, 0, stream>>>(
        gVh, gVl, WT, nullptr, nullptr, nullptr, nullptr, out);
}